// Round 10
// baseline (213.298 us; speedup 1.0000x reference)
//
#include <hip/hip_runtime.h>
#include <hip/hip_bf16.h>

typedef unsigned short u16;
typedef __bf16 bf16x8 __attribute__((ext_vector_type(8)));
typedef float f32x4 __attribute__((ext_vector_type(4)));

__device__ __forceinline__ f32x4 mfma16(bf16x8 a, bf16x8 b, f32x4 c) {
    return __builtin_amdgcn_mfma_f32_16x16x32_bf16(a, b, c, 0, 0, 0);
}

// fp32 -> bf16 bits, round-to-nearest-even
__device__ __forceinline__ u16 f2b(float x) {
    union { float f; unsigned u; } a; a.f = x;
    unsigned r = a.u + 0x7fffu + ((a.u >> 16) & 1u);
    return (u16)(r >> 16);
}
__device__ __forceinline__ unsigned f2b2(float a, float b) {
    union { __hip_bfloat162 h; unsigned u; } cv;
    cv.h = __float22bfloat162_rn(make_float2(a, b));
    return cv.u;
}
// async 16B global -> LDS (DMA, vmcnt-tracked)
__device__ __forceinline__ void async16(const u16* g, u16* l) {
    __builtin_amdgcn_global_load_lds((const __attribute__((address_space(1))) unsigned int*)g,
                                     (__attribute__((address_space(3))) unsigned int*)l, 16, 0, 0);
}

// ---------------- fused cast fp32 -> bf16 for all three inputs ----------------
#define NX  (8192 * 512)
#define NWQ (1536 * 512)
#define NWO (512 * 512)
__global__ __launch_bounds__(256) void k_cast_all(const float* __restrict__ x,
                                                  const float* __restrict__ wq,
                                                  const float* __restrict__ wo,
                                                  u16* __restrict__ xb,
                                                  u16* __restrict__ wqb,
                                                  u16* __restrict__ wob) {
    int i = (blockIdx.x * 256 + threadIdx.x) * 4;
    const float* s; u16* d; int off;
    if (i < NX)            { s = x;  d = xb;  off = i; }
    else if (i < NX + NWQ) { s = wq; d = wqb; off = i - NX; }
    else                   { s = wo; d = wob; off = i - NX - NWQ; }
    float4 f = *(const float4*)&s[off];
    uint2 o = make_uint2(f2b2(f.x, f.y), f2b2(f.z, f.w));
    *(uint2*)&d[off] = o;
}

// ---------------- QKV GEMM (async-DMA double-buffered) -----------------------
// q -> [B*H][S][64] bf16 (pre-scaled 0.125/ln2)
// k -> KF[bh][kt][kg][t][h][quad][l15][8]  (permuted QK A-frag order)
// v -> VF[bh][kt][kg][mb][quad][l15][8]    (K=32 PV A-frag order)
__global__ __launch_bounds__(256, 3) void k_gemm_qkv(const u16* __restrict__ xb,
                                                     const u16* __restrict__ wb,
                                                     const float* __restrict__ bias,
                                                     u16* __restrict__ qkvout) {
    __shared__ u16 AL[2][4096];
    __shared__ u16 WL[2][4096];
    const int tid = threadIdx.x;
    const int w = tid >> 6, lane = tid & 63, l15 = lane & 15, quad = lane >> 4;
    const int mb = blockIdx.x * 128, nb = blockIdx.y * 128;

    f32x4 acc[2][8];
#pragma unroll
    for (int i = 0; i < 2; i++)
#pragma unroll
        for (int j = 0; j < 8; j++) acc[i][j] = (f32x4){0.f, 0.f, 0.f, 0.f};

    const u16* agp = xb + (size_t)(mb + w * 32 + (lane >> 2)) * 512 + (lane & 3) * 8;
    const u16* wgp = wb + (size_t)(nb + w * 32 + (lane >> 2)) * 512 + (lane & 3) * 8;
    const int ldst = w * 1024 + lane * 8;

    async16(agp, &AL[0][ldst]);
    async16(agp + 16 * 512, &AL[0][ldst + 512]);
    async16(wgp, &WL[0][ldst]);
    async16(wgp + 16 * 512, &WL[0][ldst + 512]);
    __syncthreads();
    int p = 0;
    for (int ks = 0; ks < 16; ks++) {
        if (ks < 15) {
            int k0n = (ks + 1) * 32;
            async16(agp + k0n, &AL[p ^ 1][ldst]);
            async16(agp + 16 * 512 + k0n, &AL[p ^ 1][ldst + 512]);
            async16(wgp + k0n, &WL[p ^ 1][ldst]);
            async16(wgp + 16 * 512 + k0n, &WL[p ^ 1][ldst + 512]);
        }
        bf16x8 a0 = *(const bf16x8*)&AL[p][(w * 32 + l15) * 32 + quad * 8];
        bf16x8 a1 = *(const bf16x8*)&AL[p][(w * 32 + 16 + l15) * 32 + quad * 8];
#pragma unroll
        for (int nt = 0; nt < 8; nt++) {
            bf16x8 bfr = *(const bf16x8*)&WL[p][(nt * 16 + l15) * 32 + quad * 8];
            acc[0][nt] = mfma16(a0, bfr, acc[0][nt]);
            acc[1][nt] = mfma16(a1, bfr, acc[1][nt]);
        }
        if (ks < 15) { __syncthreads(); p ^= 1; }
    }
    const int seg = nb >> 9;          // 0=q 1=k 2=v
    u16* obase = qkvout + (size_t)seg * (16ull * 4096 * 64);
    if (seg == 0) {
        const float sc = 0.125f * 1.44269504088896340736f;
#pragma unroll
        for (int mt = 0; mt < 2; mt++)
#pragma unroll
            for (int nt = 0; nt < 8; nt++) {
                int dcol = nb + nt * 16 + l15;
                int hh = (dcol >> 6) & 7, dloc = dcol & 63;
                float bs = bias[dcol];
#pragma unroll
                for (int r = 0; r < 4; r++) {
                    int m = mb + w * 32 + mt * 16 + quad * 4 + r;
                    float vv = (acc[mt][nt][r] + bs) * sc;
                    int b = m >> 12, s = m & 4095;
                    obase[((size_t)((b * 8 + hh) * 4096 + s)) * 64 + dloc] = f2b(vv);
                }
            }
    } else if (seg == 1) {
        // permuted K frag scatter
#pragma unroll
        for (int mt = 0; mt < 2; mt++)
#pragma unroll
            for (int nt = 0; nt < 8; nt++) {
                int dcol = nb + nt * 16 + l15;
                int hh = (dcol >> 6) & 7, d = dcol & 63;
                int h2 = d >> 5, qk = (d >> 3) & 3, j = d & 7;
                float bs = bias[dcol];
                int m0 = mb + w * 32 + mt * 16 + quad * 4;
                int b = m0 >> 12, s0 = m0 & 4095;
                int kt = s0 >> 6, ksx = s0 & 63;
                int kg2 = ksx >> 5, rem = ksx & 31;
                int t2 = (rem >> 2) & 1, lb = (rem >> 3) * 4;
                size_t base = ((((((size_t)(b * 8 + hh) * 64 + kt) * 2 + kg2) * 2 + t2) * 2 + h2) * 4 + qk) * 16 + lb;
#pragma unroll
                for (int r = 0; r < 4; r++)
                    obase[(base + r) * 8 + j] = f2b(acc[mt][nt][r] + bs);
            }
    } else {
        // V frag scatter (K=32 A-operand order)
#pragma unroll
        for (int mt = 0; mt < 2; mt++)
#pragma unroll
            for (int nt = 0; nt < 8; nt++) {
                int c = nb + nt * 16 + l15;
                int hh = (c >> 6) & 7, d = c & 63;
                int mbv = d >> 4, l15v = d & 15;
                float bs = bias[c];
                int m0 = mb + w * 32 + mt * 16 + quad * 4;
                int b = m0 >> 12, si = m0 & 4095;
                int kt = si >> 6, ksx = si & 63;
                int kg2 = ksx >> 5, qv = (ksx >> 3) & 3, j0 = ksx & 7;
                uint2 o = make_uint2(f2b2(acc[mt][nt][0] + bs, acc[mt][nt][1] + bs),
                                     f2b2(acc[mt][nt][2] + bs, acc[mt][nt][3] + bs));
                size_t F = (((((size_t)(b * 8 + hh) * 64 + kt) * 2 + kg2) * 4 + mbv) * 4 + qv) * 16 + l15v;
                *(uint2*)&obase[F * 8 + j0] = o;
            }
    }
}

// ---------------- flash attention v10 (inverted-window mask) ----------------
// 256 thr = 4 waves x 32 q-rows (128-row block). BK=128: two 64-key sub-tiles
// per barrier region (wide double buffer, 64KB LDS), prefetch two tiles ahead.
// All MFMAs full-rate K=32; lsum via ones-row MFMA; P stays in registers.
__global__ __launch_bounds__(256, 2) void k_attn(const u16* __restrict__ qg,
                                                 const u16* __restrict__ kfg,
                                                 const u16* __restrict__ vfg,
                                                 u16* __restrict__ ctx,
                                                 const int* __restrict__ win) {
    __shared__ u16 KL[2][8192];   // [buf][slot*4096 + frag-linear]
    __shared__ u16 VL[2][8192];
    const int tid = threadIdx.x;
    const int w = tid >> 6, lane = tid & 63, l15 = lane & 15, quad = lane >> 4;
    const int bh = blockIdx.y;
    const int qb0 = blockIdx.x * 128;
    const int qb0w = qb0 + w * 32;
    const int W = win[0];
    const size_t bhb = (size_t)bh * 4096 * 64;

    bf16x8 qf[2][2];
#pragma unroll
    for (int g = 0; g < 2; g++) {
        const u16* qrow = &qg[bhb + (size_t)(qb0w + g * 16 + l15) * 64];
        qf[g][0] = *(const bf16x8*)&qrow[quad * 8];
        qf[g][1] = *(const bf16x8*)&qrow[32 + quad * 8];
    }
    bf16x8 ones8;
    {
        u16 v = (l15 == 0) ? (u16)0x3F80 : (u16)0;
        union { u16 a[8]; bf16x8 b; } c;
#pragma unroll
        for (int i = 0; i < 8; i++) c.a[i] = v;
        ones8 = c.b;
    }

    f32x4 O[2][4];
#pragma unroll
    for (int g = 0; g < 2; g++)
#pragma unroll
        for (int mb = 0; mb < 4; mb++) O[g][mb] = (f32x4){0.f, 0.f, 0.f, 0.f};
    f32x4 O1[2] = {(f32x4){0.f, 0.f, 0.f, 0.f}, (f32x4){0.f, 0.f, 0.f, 0.f}};

    const u16* kbase = kfg + bhb;   // [kt][4096]
    const u16* vbase = vfg + bhb;
    const int soff = w * 1024 + lane * 8;

    auto skip = [&](int kb) { return max(qb0 + 127 - kb, kb + 63 - qb0) <= W; };
    auto nextk = [&](int kb) { while (kb < 4096 && skip(kb)) kb += 64; return kb; };
    auto stage = [&](int kb, int buf, int slot) {
        const u16* kt_p = kbase + (size_t)(kb >> 6) * 4096;
        const u16* vt_p = vbase + (size_t)(kb >> 6) * 4096;
        int d = slot * 4096 + soff;
        async16(kt_p + soff, &KL[buf][d]);
        async16(kt_p + soff + 512, &KL[buf][d + 512]);
        async16(vt_p + soff, &VL[buf][d]);
        async16(vt_p + soff + 512, &VL[buf][d + 512]);
    };

    int t0 = nextk(0);
    int t1 = (t0 < 4096) ? nextk(t0 + 64) : 4096;
    if (t0 < 4096) stage(t0, 0, 0);
    if (t1 < 4096) stage(t1, 0, 1);
    __syncthreads();
    int p = 0;
    while (t0 < 4096) {
        int n0 = (t1 < 4096) ? nextk(t1 + 64) : 4096;
        int n1 = (n0 < 4096) ? nextk(n0 + 64) : 4096;
        if (n0 < 4096) stage(n0, p ^ 1, 0);
        if (n1 < 4096) stage(n1, p ^ 1, 1);

#pragma unroll
        for (int slot = 0; slot < 2; slot++) {
            int kb = slot ? t1 : t0;
            if (slot && t1 >= 4096) break;
            const u16* KLs = &KL[p][slot * 4096];
            const u16* VLs = &VL[p][slot * 4096];
            const bool partial = (kb + 63 >= qb0 - W) && (kb <= qb0 + 127 + W);
            bf16x8 kf[2][2][2];
#pragma unroll
            for (int kg = 0; kg < 2; kg++)
#pragma unroll
                for (int t = 0; t < 2; t++)
#pragma unroll
                    for (int h = 0; h < 2; h++)
                        kf[kg][t][h] = *(const bf16x8*)&KLs[((((kg * 2 + t) * 2 + h) * 4 + quad) * 16 + l15) * 8];
            bf16x8 vfr[2][4];
#pragma unroll
            for (int kg = 0; kg < 2; kg++)
#pragma unroll
                for (int mb = 0; mb < 4; mb++)
                    vfr[kg][mb] = *(const bf16x8*)&VLs[(((kg * 4 + mb) * 4 + quad) * 16 + l15) * 8];

            f32x4 C[2][2][2];
#pragma unroll
            for (int g = 0; g < 2; g++)
#pragma unroll
                for (int kg = 0; kg < 2; kg++)
#pragma unroll
                    for (int t = 0; t < 2; t++) {
                        f32x4 z = (f32x4){0.f, 0.f, 0.f, 0.f};
                        C[g][kg][t] = mfma16(kf[kg][t][0], qf[g][0], z);
                        C[g][kg][t] = mfma16(kf[kg][t][1], qf[g][1], C[g][kg][t]);
                    }
            bf16x8 pb[2][2];
            if (!partial) {
#pragma unroll
                for (int g = 0; g < 2; g++)
#pragma unroll
                    for (int kg = 0; kg < 2; kg++) {
                        float p0 = __builtin_amdgcn_exp2f(C[g][kg][0][0]);
                        float p1 = __builtin_amdgcn_exp2f(C[g][kg][0][1]);
                        float p2 = __builtin_amdgcn_exp2f(C[g][kg][0][2]);
                        float p3 = __builtin_amdgcn_exp2f(C[g][kg][0][3]);
                        float p4 = __builtin_amdgcn_exp2f(C[g][kg][1][0]);
                        float p5 = __builtin_amdgcn_exp2f(C[g][kg][1][1]);
                        float p6 = __builtin_amdgcn_exp2f(C[g][kg][1][2]);
                        float p7 = __builtin_amdgcn_exp2f(C[g][kg][1][3]);
                        union { uint4 u; bf16x8 v; } pk;
                        pk.u = make_uint4(f2b2(p0, p1), f2b2(p2, p3), f2b2(p4, p5), f2b2(p6, p7));
                        pb[g][kg] = pk.v;
                    }
            } else {
#pragma unroll
                for (int g = 0; g < 2; g++) {
                    int qr = qb0w + g * 16 + l15;
#pragma unroll
                    for (int kg = 0; kg < 2; kg++) {
                        float pv[8];
#pragma unroll
                        for (int t = 0; t < 2; t++)
#pragma unroll
                            for (int r = 0; r < 4; r++) {
                                int key = kb + kg * 32 + 8 * quad + 4 * t + r;
                                int dd = qr - key; dd = dd < 0 ? -dd : dd;
                                pv[t * 4 + r] = (dd <= W) ? 0.f
                                              : __builtin_amdgcn_exp2f(C[g][kg][t][r]);
                            }
                        union { uint4 u; bf16x8 v; } pk;
                        pk.u = make_uint4(f2b2(pv[0], pv[1]), f2b2(pv[2], pv[3]),
                                          f2b2(pv[4], pv[5]), f2b2(pv[6], pv[7]));
                        pb[g][kg] = pk.v;
                    }
                }
            }
#pragma unroll
            for (int kg = 0; kg < 2; kg++)
#pragma unroll
                for (int g = 0; g < 2; g++) {
#pragma unroll
                    for (int mb = 0; mb < 4; mb++)
                        O[g][mb] = mfma16(vfr[kg][mb], pb[g][kg], O[g][mb]);
                    O1[g] = mfma16(ones8, pb[g][kg], O1[g]);
                }
        }
        if (n0 < 4096) { __syncthreads(); p ^= 1; }
        t0 = n0; t1 = n1;
    }
    int b = bh >> 3, h = bh & 7;
#pragma unroll
    for (int g = 0; g < 2; g++) {
        float ls = __shfl(O1[g][0], l15);
        float inv = 1.0f / ls;
        int qr = qb0w + g * 16 + l15;
        size_t rowoff = ((size_t)(b * 4096 + qr)) * 512 + h * 64;
#pragma unroll
        for (int mb = 0; mb < 4; mb++) {
            uint2 o = make_uint2(f2b2(O[g][mb][0] * inv, O[g][mb][1] * inv),
                                 f2b2(O[g][mb][2] * inv, O[g][mb][3] * inv));
            *(uint2*)&ctx[rowoff + mb * 16 + quad * 4] = o;
        }
    }
}

// ---------------- out GEMM (async-DMA double-buffered) -----------------------
__global__ __launch_bounds__(256, 2) void k_gemm_out(const u16* __restrict__ ab,
                                                     const u16* __restrict__ wb,
                                                     const float* __restrict__ bias,
                                                     float* __restrict__ out) {
    __shared__ u16 AL[2][4096];
    __shared__ u16 WL[2][2048];
    const int tid = threadIdx.x;
    const int w = tid >> 6, lane = tid & 63, l15 = lane & 15, quad = lane >> 4;
    const int mb = blockIdx.x * 128, nb = blockIdx.y * 64;

    f32x4 acc[2][4];
#pragma unroll
    for (int i = 0; i < 2; i++)
#pragma unroll
        for (int j = 0; j < 4; j++) acc[i][j] = (f32x4){0.f, 0.f, 0.f, 0.f};

    const u16* agp = ab + (size_t)(mb + w * 32 + (lane >> 2)) * 512 + (lane & 3) * 8;
    const u16* wgp = wb + (size_t)(nb + w * 16 + (lane >> 2)) * 512 + (lane & 3) * 8;
    const int ldstA = w * 1024 + lane * 8;
    const int ldstW = w * 512 + lane * 8;

    async16(agp, &AL[0][ldstA]);
    async16(agp + 16 * 512, &AL[0][ldstA + 512]);
    async16(wgp, &WL[0][ldstW]);
    __syncthreads();
    int p = 0;
    for (int ks = 0; ks < 16; ks++) {
        if (ks < 15) {
            int k0n = (ks + 1) * 32;
            async16(agp + k0n, &AL[p ^ 1][ldstA]);
            async16(agp + 16 * 512 + k0n, &AL[p ^ 1][ldstA + 512]);
            async16(wgp + k0n, &WL[p ^ 1][ldstW]);
        }
        bf16x8 a0 = *(const bf16x8*)&AL[p][(w * 32 + l15) * 32 + quad * 8];
        bf16x8 a1 = *(const bf16x8*)&AL[p][(w * 32 + 16 + l15) * 32 + quad * 8];
#pragma unroll
        for (int nt = 0; nt < 4; nt++) {
            bf16x8 bfr = *(const bf16x8*)&WL[p][(nt * 16 + l15) * 32 + quad * 8];
            acc[0][nt] = mfma16(a0, bfr, acc[0][nt]);
            acc[1][nt] = mfma16(a1, bfr, acc[1][nt]);
        }
        if (ks < 15) { __syncthreads(); p ^= 1; }
    }
#pragma unroll
    for (int mt = 0; mt < 2; mt++)
#pragma unroll
        for (int nt = 0; nt < 4; nt++) {
            int n = nb + nt * 16 + l15;
            float bs = bias[n];
#pragma unroll
            for (int r = 0; r < 4; r++) {
                int m = mb + w * 32 + mt * 16 + quad * 4 + r;
                out[(size_t)m * 512 + n] = acc[mt][nt][r] + bs;
            }
        }
}

extern "C" void kernel_launch(void* const* d_in, const int* in_sizes, int n_in,
                              void* d_out, int out_size, void* d_ws, size_t ws_size,
                              hipStream_t stream) {
    const float* x    = (const float*)d_in[0];
    const float* wqkv = (const float*)d_in[1];
    const float* bqkv = (const float*)d_in[2];
    const float* wout = (const float*)d_in[3];
    const float* bout = (const float*)d_in[4];
    const int*   win  = (const int*)d_in[5];
    float* out = (float*)d_out;

    u16* xb    = (u16*)d_ws;
    u16* wqkvb = xb    + 8192ull * 512;
    u16* woutb = wqkvb + 1536ull * 512;
    u16* qkvb  = woutb + 512ull * 512;
    u16* ctxb  = qkvb  + 3ull * 16 * 4096 * 64;

    k_cast_all<<<5120, 256, 0, stream>>>(x, wqkv, wout, xb, wqkvb, woutb);
    k_gemm_qkv<<<dim3(64, 12), 256, 0, stream>>>(xb, wqkvb, bqkv, qkvb);
    k_attn<<<dim3(32, 16), 256, 0, stream>>>(qkvb, qkvb + 16ull * 4096 * 64,
                                             qkvb + 32ull * 4096 * 64, ctxb, win);
    k_gemm_out<<<dim3(64, 8), 256, 0, stream>>>(ctxb, woutb, bout, out);
}